// Round 14
// baseline (183.146 us; speedup 1.0000x reference)
//
#include <hip/hip_runtime.h>
#include <cstdint>

typedef short s16x8 __attribute__((ext_vector_type(8)));
typedef short s16x4 __attribute__((ext_vector_type(4)));
typedef unsigned short u16x4 __attribute__((ext_vector_type(4)));
typedef float f32x4 __attribute__((ext_vector_type(4)));
typedef float f32x16 __attribute__((ext_vector_type(16)));
typedef unsigned int u32x4 __attribute__((ext_vector_type(4)));

#define ND 1024
#define NH 16
#define DH 64
#define NQ 2048
#define NL 2560
#define MMAIN 4096
#define MCAT 4608
// 0.125 (1/sqrt(64)) * log2(e): softmax runs in exp2 domain
#define Q_SCALE 0.18033688011112042f

__device__ __forceinline__ unsigned short f2b(float f) {
  unsigned u = __builtin_bit_cast(unsigned, f);
  u += 0x7FFFu + ((u >> 16) & 1u);
  return (unsigned short)(u >> 16);
}

__device__ __forceinline__ void gload16(const void* g, void* l) {
  __builtin_amdgcn_global_load_lds(
      (const __attribute__((address_space(1))) void*)(unsigned long long)(uintptr_t)g,
      (__attribute__((address_space(3))) void*)(unsigned)(uintptr_t)l,
      16, 0, 0);
}

__device__ __forceinline__ f32x4 mfma16(s16x8 a, s16x8 b, f32x4 c) {
  return __builtin_amdgcn_mfma_f32_16x16x32_bf16(a, b, c, 0, 0, 0);
}
__device__ __forceinline__ f32x16 mfma32(s16x8 a, s16x8 b, f32x16 c) {
  return __builtin_amdgcn_mfma_f32_32x32x16_bf16(a, b, c, 0, 0, 0);
}

// raw HW exp2: |x| <= ~35 exp2-units here, safe
__device__ __forceinline__ float exp2r(float x) {
  float r;
  asm("v_exp_f32 %0, %1" : "=v"(r) : "v"(x));
  return r;
}

__device__ __forceinline__ int sext_bit(unsigned w, int c) {
#if __has_builtin(__builtin_amdgcn_sbfe)
  return __builtin_amdgcn_sbfe((int)w, c, 1);
#else
  return -(int)((w >> c) & 1u);
#endif
}

__device__ __forceinline__ unsigned cvt_pk_bf16(float lo, float hi) {
  unsigned d;
  asm("v_cvt_pk_bf16_f32 %0, %1, %2" : "=v"(d) : "v"(lo), "v"(hi));
  return d;
}

// swaps a[lanes 32..63] <-> b[lanes 0..31]  (m214 v22 semantics)
__device__ __forceinline__ void plane32_swap(unsigned& a, unsigned& b) {
  asm("v_permlane32_swap_b32 %0, %1" : "+v"(a), "+v"(b));
}

__device__ __forceinline__ f32x16 z16() {
  f32x16 v;
#pragma unroll
  for (int i = 0; i < 16; ++i) v[i] = 0.f;
  return v;
}

// ---------------- fused prep: convert x | transpose W | pack mask ----------------
// grid 6912 = 4608 convert + 1024 transpose + 1280 pack (one launch, overlapped).

__global__ __launch_bounds__(256) void k_prep(const float* __restrict__ mainp,
                                              const float* __restrict__ sidep,
                                              const int* __restrict__ mask,
                                              const float* __restrict__ W0,
                                              const float* __restrict__ W1,
                                              const float* __restrict__ W2,
                                              const float* __restrict__ W3,
                                              short* __restrict__ xcat,
                                              short* __restrict__ Wt,
                                              unsigned* __restrict__ pm) {
  __shared__ float T[64][65];
  const int bid = blockIdx.x;
  const int tid = threadIdx.x;
  if (bid < 4608) {
    // ---- convert [main;side] f32 -> bf16 ----
    size_t i4 = ((size_t)bid * 256 + tid) * 4;
    const float* src =
        (i4 < (size_t)MMAIN * ND) ? (mainp + i4) : (sidep + (i4 - (size_t)MMAIN * ND));
    float4 v = *(const float4*)src;
    s16x4 o;
    o[0] = (short)f2b(v.x); o[1] = (short)f2b(v.y);
    o[2] = (short)f2b(v.z); o[3] = (short)f2b(v.w);
    *(s16x4*)(xcat + i4) = o;
  } else if (bid < 4608 + 1024) {
    // ---- transpose-convert W -> Wt[n][k] bf16 ----
    const int id = bid - 4608;
    const int z = id >> 8, rem = id & 255;
    const float* W = z == 0 ? W0 : z == 1 ? W1 : z == 2 ? W2 : W3;
    short* out = Wt + (size_t)z * (ND * ND);
    const int r = tid >> 2, c0 = (tid & 3) * 16;
    const int k0 = (rem & 15) * 64, n0 = (rem >> 4) * 64;
#pragma unroll
    for (int i = 0; i < 4; ++i) {
      float4 v = *(const float4*)(W + (size_t)(k0 + r) * ND + n0 + c0 + i * 4);
      T[r][c0 + i * 4 + 0] = v.x; T[r][c0 + i * 4 + 1] = v.y;
      T[r][c0 + i * 4 + 2] = v.z; T[r][c0 + i * 4 + 3] = v.w;
    }
    __syncthreads();
    s16x8 o0, o1;
#pragma unroll
    for (int i = 0; i < 8; ++i) o0[i] = (short)f2b(T[c0 + i][r]);
#pragma unroll
    for (int i = 0; i < 8; ++i) o1[i] = (short)f2b(T[c0 + 8 + i][r]);
    *(s16x8*)(out + (size_t)(n0 + r) * ND + k0 + c0) = o0;
    *(s16x8*)(out + (size_t)(n0 + r) * ND + k0 + c0 + 8) = o1;
  } else {
    // ---- pack mask to 1 bit ----
    const int W = (bid - 5632) * 256 + tid;
    const int4* src = (const int4*)(mask + (size_t)W * 32);
    unsigned bits = 0;
#pragma unroll
    for (int i = 0; i < 8; ++i) {
      int4 v = src[i];
      bits |= (unsigned)(v.x & 1) << (i * 4 + 0);
      bits |= (unsigned)(v.y & 1) << (i * 4 + 1);
      bits |= (unsigned)(v.z & 1) << (i * 4 + 2);
      bits |= (unsigned)(v.w & 1) << (i * 4 + 3);
    }
    pm[W] = bits;
  }
}

// ---------------- merged QKV GEMM: C[m,n] = A @ Wt[n,:]^T, n in [0,3072) ----------------
// grid 24x36 = 864 blocks; XCD-bijective swizzle (864 = 8*108).
// R14: V-blocks (n0 >= 2048) transpose their output tile through LDS so the
// vt stores are contiguous along p (256B segments) instead of 8B-per-5KB
// scatter (8x write amplification, ~70MB extra HBM writes). Numerics identical.

__global__ __launch_bounds__(256) void k_gemm_qkv(const short* __restrict__ A,
                                                  const short* __restrict__ Bt,
                                                  const float* __restrict__ bqp,
                                                  const float* __restrict__ bkp,
                                                  const float* __restrict__ bvp,
                                                  short* __restrict__ qb,
                                                  short* __restrict__ kb,
                                                  short* __restrict__ vt) {
  __shared__ __align__(16) short As[128 * 64];
  __shared__ __align__(16) short Bs[128 * 64];
  const int tid = threadIdx.x;
  const int w = tid >> 6, l = tid & 63;
  const int lg = l >> 4, li = l & 15;
  const int wr = w >> 1, wc = w & 1;
  const int fid = blockIdx.x + 24 * blockIdx.y;
  const int rid = (fid & 7) * 108 + (fid >> 3);
  const int m0 = (rid / 24) * 128, n0 = (rid % 24) * 128;

  f32x4 acc[4][4];
#pragma unroll
  for (int i = 0; i < 4; ++i)
#pragma unroll
    for (int j = 0; j < 4; ++j) acc[i][j] = (f32x4){0.f, 0.f, 0.f, 0.f};

  const int cb = (l & 7) ^ (l >> 3);
  const int rsub = l >> 3;

  for (int kt = 0; kt < 16; ++kt) {
    __syncthreads();
#pragma unroll
    for (int i = 0; i < 4; ++i) {
      int c = w * 4 + i;
      int rr = c * 8 + rsub;
      gload16(A + (size_t)(m0 + rr) * ND + kt * 64 + cb * 8, As + c * 512);
      gload16(Bt + (size_t)(n0 + rr) * ND + kt * 64 + cb * 8, Bs + c * 512);
    }
    __syncthreads();
#pragma unroll
    for (int kk = 0; kk < 2; ++kk) {
      const int blk = (((kk * 4) + lg) ^ (l & 7)) * 8;
      s16x8 af[4], bf[4];
#pragma unroll
      for (int mf = 0; mf < 4; ++mf)
        af[mf] = *(const s16x8*)(As + (wr * 64 + mf * 16 + li) * 64 + blk);
#pragma unroll
      for (int nf = 0; nf < 4; ++nf)
        bf[nf] = *(const s16x8*)(Bs + (wc * 64 + nf * 16 + li) * 64 + blk);
#pragma unroll
      for (int mf = 0; mf < 4; ++mf)
#pragma unroll
        for (int nf = 0; nf < 4; ++nf)
          acc[mf][nf] = mfma16(af[mf], bf[nf], acc[mf][nf]);
    }
  }

  if (n0 < 2048) {
    // ---- Q/K epilogue (proj 0/1 only; unchanged from R13) ----
#pragma unroll
    for (int mf = 0; mf < 4; ++mf) {
#pragma unroll
      for (int nf = 0; nf < 4; ++nf) {
        const int n = n0 + wc * 64 + nf * 16 + li;
        const int proj = n >> 10, nn = n & 1023;
        const int h = nn >> 6, dd = nn & 63;
        const float bn = (proj == 0 ? bqp : bkp)[nn];
        const int mbase = m0 + wr * 64 + mf * 16 + lg * 4;
        if (proj == 0) {
          if (mbase < MMAIN) {
#pragma unroll
            for (int r = 0; r < 4; ++r) {
              int m = mbase + r;
              int b = m >> 11, q = m & 2047;
              qb[((size_t)(b * NH + h) * NQ + q) * DH + dd] =
                  (short)f2b((acc[mf][nf][r] + bn) * Q_SCALE);
            }
          }
        } else {
#pragma unroll
          for (int r = 0; r < 4; ++r) {
            int m = mbase + r;
            short v = (short)f2b(acc[mf][nf][r] + bn);
            if (m < MMAIN) {
              int b = m >> 11, p = m & 2047;
              kb[((size_t)(b * NH + h) * NL + p) * DH + dd] = v;
            } else {
              int p = NQ + (m - MMAIN);
              kb[((size_t)h * NL + p) * DH + dd] = v;
              kb[((size_t)(NH + h) * NL + p) * DH + dd] = v;
            }
          }
        }
      }
    }
  } else {
    // ---- V epilogue: LDS-transposed, coalesced along p ----
    // 4 phases of 32 n-columns; Tl[32][136] bf16 (8.7KB, reuses As; +8 pad
    // breaks the 256B-stride bank conflict on writes).
    short* Tl = As;
#pragma unroll
    for (int ph = 0; ph < 4; ++ph) {
      __syncthreads();  // phase 0: also protects last K-loop reads of As
      if (wc == (ph >> 1)) {
#pragma unroll
        for (int j = 0; j < 2; ++j) {
          const int nf = 2 * (ph & 1) + j;
          const int nloc = j * 16 + li;
          const int nn = (n0 + wc * 64 + nf * 16 + li) & 1023;
          const float bn = bvp[nn];
#pragma unroll
          for (int mf = 0; mf < 4; ++mf) {
            const int mbase = wr * 64 + mf * 16 + lg * 4;
            u16x4 vv;
#pragma unroll
            for (int r = 0; r < 4; ++r) vv[r] = f2b(acc[mf][nf][r] + bn);
            *(u16x4*)(Tl + nloc * 136 + mbase) = vv;
          }
        }
      }
      __syncthreads();
      // coalesced store: 512 chunks of 16B (8 shorts along p), 2 per thread
#pragma unroll
      for (int t0 = 0; t0 < 2; ++t0) {
        const int t = tid + t0 * 256;
        const int nl = t >> 4, c = t & 15;
        s16x8 v8 = *(const s16x8*)(Tl + nl * 136 + c * 8);
        const int nn = (n0 + ph * 32 + nl) & 1023;
        const int h = nn >> 6, dd = nn & 63;
        const int m = m0 + c * 8;
        if (m0 < MMAIN) {
          const int b = m0 >> 11, p = m & 2047;
          *(s16x8*)(vt + ((size_t)(b * NH + h) * DH + dd) * NL + p) = v8;
        } else {
          const int p = NQ + (m - MMAIN);
          *(s16x8*)(vt + ((size_t)h * DH + dd) * NL + p) = v8;
          *(s16x8*)(vt + ((size_t)(NH + h) * DH + dd) * NL + p) = v8;
        }
      }
    }
  }
}

// ---------------- output GEMM: f32 out + bias ----------------
// 128x64 tile, grid (16 n, 32 m) = 512 blocks = 2 blocks/CU. XCD swizzle 512 = 8*64.

__global__ __launch_bounds__(256) void k_gemm_out(const short* __restrict__ A,
                                                  const short* __restrict__ Bt,
                                                  const float* __restrict__ bias,
                                                  float* __restrict__ outp) {
  __shared__ __align__(16) short As[128 * 64];
  __shared__ __align__(16) short Bs[64 * 64];
  const int tid = threadIdx.x;
  const int w = tid >> 6, l = tid & 63;
  const int lg = l >> 4, li = l & 15;
  const int wr = w >> 1, wc = w & 1;
  const int fid = blockIdx.x + 16 * blockIdx.y;
  const int rid = (fid & 7) * 64 + (fid >> 3);
  const int m0 = (rid >> 4) * 128, n0 = (rid & 15) * 64;

  f32x4 acc[4][2];
#pragma unroll
  for (int i = 0; i < 4; ++i)
#pragma unroll
    for (int j = 0; j < 2; ++j) acc[i][j] = (f32x4){0.f, 0.f, 0.f, 0.f};

  const int cb = (l & 7) ^ (l >> 3);
  const int rsub = l >> 3;

  for (int kt = 0; kt < 16; ++kt) {
    __syncthreads();
#pragma unroll
    for (int i = 0; i < 4; ++i) {
      int c = w * 4 + i;
      int rr = c * 8 + rsub;
      gload16(A + (size_t)(m0 + rr) * ND + kt * 64 + cb * 8, As + c * 512);
    }
#pragma unroll
    for (int i = 0; i < 2; ++i) {
      int c = w * 2 + i;
      int rr = c * 8 + rsub;
      gload16(Bt + (size_t)(n0 + rr) * ND + kt * 64 + cb * 8, Bs + c * 512);
    }
    __syncthreads();
#pragma unroll
    for (int kk = 0; kk < 2; ++kk) {
      const int blk = (((kk * 4) + lg) ^ (l & 7)) * 8;
      s16x8 af[4], bf[2];
#pragma unroll
      for (int mf = 0; mf < 4; ++mf)
        af[mf] = *(const s16x8*)(As + (wr * 64 + mf * 16 + li) * 64 + blk);
#pragma unroll
      for (int nf = 0; nf < 2; ++nf)
        bf[nf] = *(const s16x8*)(Bs + (wc * 32 + nf * 16 + li) * 64 + blk);
#pragma unroll
      for (int mf = 0; mf < 4; ++mf)
#pragma unroll
        for (int nf = 0; nf < 2; ++nf)
          acc[mf][nf] = mfma16(af[mf], bf[nf], acc[mf][nf]);
    }
  }

#pragma unroll
  for (int mf = 0; mf < 4; ++mf) {
#pragma unroll
    for (int nf = 0; nf < 2; ++nf) {
      const int n = n0 + wc * 32 + nf * 16 + li;
      const float bn = bias[n];
      const int mbase = m0 + wr * 64 + mf * 16 + lg * 4;
#pragma unroll
      for (int r = 0; r < 4; ++r)
        outp[(size_t)(mbase + r) * ND + n] = acc[mf][nf][r] + bn;
    }
  }
}

// ---------------- flash attention (32x32 MFMA, swapped QK^T, no-max softmax) ----
// grid (bh=32, qt=16), 512 threads = 8 waves = 4 q-subtiles x 2 kv-groups.
// KV tile = 32 rows; LDS 32KB/block -> 2 blocks/CU = 16 waves/CU.
// Sync structure: __syncthreads-per-tile (R12's counted-vmcnt ring raced).

#define PROC_TILE(STV, WSV, PB0, PB1)                                        \
  do {                                                                       \
    unsigned pk_[8];                                                         \
    _Pragma("unroll") for (int r_ = 0; r_ < 16; ++r_) {                      \
      const int c_ = (r_ & 3) + 8 * (r_ >> 2);                               \
      float p_ = exp2r(STV[r_]);                                             \
      p_ = __builtin_bit_cast(float, __builtin_bit_cast(unsigned, p_) &      \
                                         (unsigned)sext_bit(WSV, c_));       \
      lr += p_;                                                              \
      STV[r_] = p_;                                                          \
    }                                                                        \
    _Pragma("unroll") for (int m_ = 0; m_ < 8; ++m_)                         \
        pk_[m_] = cvt_pk_bf16(STV[2 * m_], STV[2 * m_ + 1]);                 \
    plane32_swap(pk_[0], pk_[2]);                                            \
    plane32_swap(pk_[1], pk_[3]);                                            \
    plane32_swap(pk_[4], pk_[6]);                                            \
    plane32_swap(pk_[5], pk_[7]);                                            \
    {                                                                        \
      u32x4 t_ = {pk_[0], pk_[1], pk_[2], pk_[3]};                           \
      PB0 = __builtin_bit_cast(s16x8, t_);                                   \
    }                                                                        \
    {                                                                        \
      u32x4 t_ = {pk_[4], pk_[5], pk_[6], pk_[7]};                           \
      PB1 = __builtin_bit_cast(s16x8, t_);                                   \
    }                                                                        \
  } while (0)

#define ATTN_TILE(CUR, T, DONEXT)                                            \
  do {                                                                       \
    unsigned mw_ = pmrow[(T)];                                               \
    if (DONEXT) {                                                            \
      gload16(kg + (size_t)((T) + 1) * 2048, kl + ((CUR) ^ 1) * 4096);       \
      gload16(vg + ((T) + 1) * 32, vl + ((CUR) ^ 1) * 4096);                 \
    }                                                                        \
    f32x16 st_;                                                              \
    __builtin_amdgcn_s_setprio(1);                                           \
    st_ = mfma32(*(const s16x8*)(ldsg + (CUR) * 4096 + koff[0]), qa[0], ZACC); \
    st_ = mfma32(*(const s16x8*)(ldsg + (CUR) * 4096 + koff[1]), qa[1], st_);  \
    st_ = mfma32(*(const s16x8*)(ldsg + (CUR) * 4096 + koff[2]), qa[2], st_);  \
    st_ = mfma32(*(const s16x8*)(ldsg + (CUR) * 4096 + koff[3]), qa[3], st_);  \
    __builtin_amdgcn_s_setprio(0);                                           \
    unsigned ws_ = mw_ >> (hi * 4);                                          \
    s16x8 pb0_, pb1_;                                                        \
    PROC_TILE(st_, ws_, pb0_, pb1_);                                         \
    __builtin_amdgcn_s_setprio(1);                                           \
    {                                                                        \
      s16x8 v0_ = *(const s16x8*)(ldsg + 8192 + (CUR) * 4096 + voff[0]);     \
      s16x8 v1_ =                                                            \
          *(const s16x8*)(ldsg + 8192 + (CUR) * 4096 + voff[0] + 2048);      \
      ot0 = mfma32(v0_, pb0_, ot0);                                          \
      ot1 = mfma32(v1_, pb0_, ot1);                                          \
    }                                                                        \
    {                                                                        \
      s16x8 v0_ = *(const s16x8*)(ldsg + 8192 + (CUR) * 4096 + voff[1]);     \
      s16x8 v1_ =                                                            \
          *(const s16x8*)(ldsg + 8192 + (CUR) * 4096 + voff[1] + 2048);      \
      ot0 = mfma32(v0_, pb1_, ot0);                                          \
      ot1 = mfma32(v1_, pb1_, ot1);                                          \
    }                                                                        \
    __builtin_amdgcn_s_setprio(0);                                           \
    __syncthreads();                                                         \
  } while (0)

__global__ __launch_bounds__(512, 2) void k_attn2(const short* __restrict__ qbuf,
                                                  const short* __restrict__ kbuf,
                                                  const short* __restrict__ vtbuf,
                                                  const unsigned* __restrict__ pmask,
                                                  short* __restrict__ attbuf) {
  // 32KB: 2 groups x { K[2][32][64] @0, V^T[2][64][32] @8192 }
  __shared__ __align__(16) short lds[16384];
  char* ldsb = (char*)lds;

  const int tid = threadIdx.x;
  const int w = tid >> 6, l = tid & 63;
  const int wg = w & 3, g = w >> 2;  // q-subtile, kv-group
  const int li = l & 31, hi = l >> 5;
  const int bh = blockIdx.x;
  const int b = bh >> 4, h = bh & 15;
  const int qr0 = blockIdx.y * 128 + wg * 32;
  const size_t bhs = (size_t)bh;
  char* ldsg = ldsb + g * 16384;

  // Q fragments (q pre-scaled by log2e/8): lane covers q = qr0+li, d = ks*16+hi*8
  s16x8 qa[4];
  {
    const short* qp = qbuf + (bhs * NQ + qr0 + li) * DH + hi * 8;
#pragma unroll
    for (int ks = 0; ks < 4; ++ks) qa[ks] = *(const s16x8*)(qp + ks * 16);
  }

  // K fragment offsets (rows 128B, XOR(li&7) swizzle): row=li, slice=2ks+hi
  int koff[4];
#pragma unroll
  for (int ks = 0; ks < 4; ++ks)
    koff[ks] = li * 128 + ((((ks << 1) | hi) ^ (li & 7)) << 4);

  // V fragment offsets (rows 64B, XOR((li>>1)&3) swizzle): row=d=li, slice=2ks2+hi
  int voff[2];
#pragma unroll
  for (int ks2 = 0; ks2 < 2; ++ks2)
    voff[ks2] = li * 64 + ((((ks2 << 1) | hi) ^ ((li >> 1) & 3)) << 4);

  // staging (per tile per group: K 4KB + V 4KB; each wave 1KB of each)
  const short* kg = kbuf + (bhs * NL + g * 1280 + wg * 8 + (l >> 3)) * DH +
                    (((l & 7) ^ (l >> 3)) << 3);
  const short* vg = vtbuf + (bhs * DH + wg * 16 + (l >> 2)) * NL + g * 1280 +
                    (((l & 3) ^ ((l >> 3) & 3)) << 3);
  char* kl = ldsg + wg * 1024;
  char* vl = ldsg + 8192 + wg * 1024;

  const unsigned* pmrow = pmask + ((size_t)b * NQ + qr0 + li) * 80 + g * 40;

  const f32x16 ZACC = z16();
  f32x16 ot0 = z16(), ot1 = z16();
  float lr = 0.f;

  // prologue: stage tile 0 into buffer 0
  gload16(kg, kl);
  gload16(vg, vl);
  __syncthreads();

  for (int tt = 0; tt < 20; ++tt) {
    const int t0 = 2 * tt;
    ATTN_TILE(0, t0, 1);
    ATTN_TILE(1, t0 + 1, (t0 + 2 < 40));
  }

  // finish l: this lane held k-rows for its hi half only
  lr += __shfl_xor(lr, 32);

  // ---- combine the two KV groups (exact: no-max partials are additive) ----
  // 2 phases (each phase: 2 waves x 64 lanes x 33 f32 = 16.9KB).
  float* comb = (float*)ldsb;
  const int half = wg >> 1;
  const int slot = ((wg & 1) * 64 + l) * 33;  // stride 33: 2-way alias only
  float lsum = lr;
#pragma unroll
  for (int ph = 0; ph < 2; ++ph) {
    __syncthreads();
    if (g == 1 && half == ph) {
#pragma unroll
      for (int i = 0; i < 16; ++i) comb[slot + i] = ot0[i];
#pragma unroll
      for (int i = 0; i < 16; ++i) comb[slot + 16 + i] = ot1[i];
      comb[slot + 32] = lr;
    }
    __syncthreads();
    if (g == 0 && half == ph) {
#pragma unroll
      for (int i = 0; i < 16; ++i) ot0[i] += comb[slot + i];
#pragma unroll
      for (int i = 0; i < 16; ++i) ot1[i] += comb[slot + 16 + i];
      lsum += comb[slot + 32];
    }
  }
  if (g == 0) {
    const float inv = 1.0f / lsum;
    // epilogue: O^T[d][q] -> attbuf[b,q,h*64+d], d = dt*32 + 8gg + 4hi + r
    short* orow = attbuf + ((size_t)b * NQ + qr0 + li) * ND + h * 64;
#pragma unroll
    for (int gg = 0; gg < 4; ++gg) {
      u16x4 v0, v1;
#pragma unroll
      for (int r = 0; r < 4; ++r) {
        v0[r] = f2b(ot0[gg * 4 + r] * inv);
        v1[r] = f2b(ot1[gg * 4 + r] * inv);
      }
      *(u16x4*)(orow + gg * 8 + hi * 4) = v0;
      *(u16x4*)(orow + 32 + gg * 8 + hi * 4) = v1;
    }
  }
}

// ---------------- host ----------------

extern "C" void kernel_launch(void* const* d_in, const int* in_sizes, int n_in,
                              void* d_out, int out_size, void* d_ws, size_t ws_size,
                              hipStream_t stream) {
  const float* mainp = (const float*)d_in[0];
  const float* sidep = (const float*)d_in[1];
  const int* mask = (const int*)d_in[2];
  const float* Wq = (const float*)d_in[3];
  const float* bq = (const float*)d_in[4];
  const float* Wk = (const float*)d_in[5];
  const float* bk = (const float*)d_in[6];
  const float* Wv = (const float*)d_in[7];
  const float* bv = (const float*)d_in[8];
  const float* Wo = (const float*)d_in[9];
  const float* bo = (const float*)d_in[10];

  char* ws = (char*)d_ws;
  short* xcat   = (short*)(ws + 0);             //  9,437,184 B
  short* Wt     = (short*)(ws + 9437184);       //  8,388,608 B (4x 1024x1024 bf16, n-major)
  short* qbuf   = (short*)(ws + 17825792);      //  8,388,608 B [b,h,q,d]
  short* kbuf   = (short*)(ws + 26214400);      // 10,485,760 B [b,h,pos,d]
  short* vtbuf  = (short*)(ws + 36700160);      // 10,485,760 B [b,h,d,pos]
  short* attbuf = (short*)(ws + 47185920);      //  8,388,608 B [b*q, D]
  unsigned* pmask = (unsigned*)(ws + 55574528); //  1,310,720 B

  k_prep<<<6912, 256, 0, stream>>>(mainp, sidep, mask, Wq, Wk, Wv, Wo,
                                   xcat, Wt, pmask);

  k_gemm_qkv<<<dim3(24, 36), 256, 0, stream>>>(xcat, Wt, bq, bk, bv, qbuf, kbuf, vtbuf);

  k_attn2<<<dim3(32, 16), 512, 0, stream>>>(qbuf, kbuf, vtbuf, pmask, attbuf);

  k_gemm_out<<<dim3(16, 32), 256, 0, stream>>>(attbuf, Wt + 3145728, bo, (float*)d_out);
}

// Round 15
// 148.165 us; speedup vs baseline: 1.2361x; 1.2361x over previous
//
#include <hip/hip_runtime.h>
#include <cstdint>

typedef short s16x8 __attribute__((ext_vector_type(8)));
typedef short s16x4 __attribute__((ext_vector_type(4)));
typedef unsigned short u16x4 __attribute__((ext_vector_type(4)));
typedef float f32x4 __attribute__((ext_vector_type(4)));
typedef float f32x16 __attribute__((ext_vector_type(16)));
typedef unsigned int u32x4 __attribute__((ext_vector_type(4)));

#define ND 1024
#define NH 16
#define DH 64
#define NQ 2048
#define NL 2560
#define MMAIN 4096
#define MCAT 4608
// 0.125 (1/sqrt(64)) * log2(e): softmax runs in exp2 domain
#define Q_SCALE 0.18033688011112042f

__device__ __forceinline__ unsigned short f2b(float f) {
  unsigned u = __builtin_bit_cast(unsigned, f);
  u += 0x7FFFu + ((u >> 16) & 1u);
  return (unsigned short)(u >> 16);
}

__device__ __forceinline__ void gload16(const void* g, void* l) {
  __builtin_amdgcn_global_load_lds(
      (const __attribute__((address_space(1))) void*)(unsigned long long)(uintptr_t)g,
      (__attribute__((address_space(3))) void*)(unsigned)(uintptr_t)l,
      16, 0, 0);
}

__device__ __forceinline__ f32x4 mfma16(s16x8 a, s16x8 b, f32x4 c) {
  return __builtin_amdgcn_mfma_f32_16x16x32_bf16(a, b, c, 0, 0, 0);
}
__device__ __forceinline__ f32x16 mfma32(s16x8 a, s16x8 b, f32x16 c) {
  return __builtin_amdgcn_mfma_f32_32x32x16_bf16(a, b, c, 0, 0, 0);
}

// raw HW exp2: |x| <= ~35 exp2-units here, safe
__device__ __forceinline__ float exp2r(float x) {
  float r;
  asm("v_exp_f32 %0, %1" : "=v"(r) : "v"(x));
  return r;
}

__device__ __forceinline__ int sext_bit(unsigned w, int c) {
#if __has_builtin(__builtin_amdgcn_sbfe)
  return __builtin_amdgcn_sbfe((int)w, c, 1);
#else
  return -(int)((w >> c) & 1u);
#endif
}

__device__ __forceinline__ unsigned cvt_pk_bf16(float lo, float hi) {
  unsigned d;
  asm("v_cvt_pk_bf16_f32 %0, %1, %2" : "=v"(d) : "v"(lo), "v"(hi));
  return d;
}

// swaps a[lanes 32..63] <-> b[lanes 0..31]  (m214 v22 semantics)
__device__ __forceinline__ void plane32_swap(unsigned& a, unsigned& b) {
  asm("v_permlane32_swap_b32 %0, %1" : "+v"(a), "+v"(b));
}

__device__ __forceinline__ f32x16 z16() {
  f32x16 v;
#pragma unroll
  for (int i = 0; i < 16; ++i) v[i] = 0.f;
  return v;
}

// ---------------- fused prep: convert x | transpose W | pack mask ----------------
// grid 6912 = 4608 convert + 1024 transpose + 1280 pack (one launch, overlapped).

__global__ __launch_bounds__(256) void k_prep(const float* __restrict__ mainp,
                                              const float* __restrict__ sidep,
                                              const int* __restrict__ mask,
                                              const float* __restrict__ W0,
                                              const float* __restrict__ W1,
                                              const float* __restrict__ W2,
                                              const float* __restrict__ W3,
                                              short* __restrict__ xcat,
                                              short* __restrict__ Wt,
                                              unsigned* __restrict__ pm) {
  __shared__ float T[64][65];
  const int bid = blockIdx.x;
  const int tid = threadIdx.x;
  if (bid < 4608) {
    // ---- convert [main;side] f32 -> bf16 ----
    size_t i4 = ((size_t)bid * 256 + tid) * 4;
    const float* src =
        (i4 < (size_t)MMAIN * ND) ? (mainp + i4) : (sidep + (i4 - (size_t)MMAIN * ND));
    float4 v = *(const float4*)src;
    s16x4 o;
    o[0] = (short)f2b(v.x); o[1] = (short)f2b(v.y);
    o[2] = (short)f2b(v.z); o[3] = (short)f2b(v.w);
    *(s16x4*)(xcat + i4) = o;
  } else if (bid < 4608 + 1024) {
    // ---- transpose-convert W -> Wt[n][k] bf16 ----
    const int id = bid - 4608;
    const int z = id >> 8, rem = id & 255;
    const float* W = z == 0 ? W0 : z == 1 ? W1 : z == 2 ? W2 : W3;
    short* out = Wt + (size_t)z * (ND * ND);
    const int r = tid >> 2, c0 = (tid & 3) * 16;
    const int k0 = (rem & 15) * 64, n0 = (rem >> 4) * 64;
#pragma unroll
    for (int i = 0; i < 4; ++i) {
      float4 v = *(const float4*)(W + (size_t)(k0 + r) * ND + n0 + c0 + i * 4);
      T[r][c0 + i * 4 + 0] = v.x; T[r][c0 + i * 4 + 1] = v.y;
      T[r][c0 + i * 4 + 2] = v.z; T[r][c0 + i * 4 + 3] = v.w;
    }
    __syncthreads();
    s16x8 o0, o1;
#pragma unroll
    for (int i = 0; i < 8; ++i) o0[i] = (short)f2b(T[c0 + i][r]);
#pragma unroll
    for (int i = 0; i < 8; ++i) o1[i] = (short)f2b(T[c0 + 8 + i][r]);
    *(s16x8*)(out + (size_t)(n0 + r) * ND + k0 + c0) = o0;
    *(s16x8*)(out + (size_t)(n0 + r) * ND + k0 + c0 + 8) = o1;
  } else {
    // ---- pack mask to 1 bit ----
    const int W = (bid - 5632) * 256 + tid;
    const int4* src = (const int4*)(mask + (size_t)W * 32);
    unsigned bits = 0;
#pragma unroll
    for (int i = 0; i < 8; ++i) {
      int4 v = src[i];
      bits |= (unsigned)(v.x & 1) << (i * 4 + 0);
      bits |= (unsigned)(v.y & 1) << (i * 4 + 1);
      bits |= (unsigned)(v.z & 1) << (i * 4 + 2);
      bits |= (unsigned)(v.w & 1) << (i * 4 + 3);
    }
    pm[W] = bits;
  }
}

// ---------------- merged QKV GEMM: C[m,n] = A @ Wt[n,:]^T, n in [0,3072) ----------------
// grid 24x36 = 864 blocks; XCD-bijective swizzle (864 = 8*108).
// R15 = R13 epilogue (unified scatter). R14's V-transpose epilogue crossed the
// 128-VGPR cliff (140 regs -> waves/CU halved -> HBM latency-bound, 52->91us).

__global__ __launch_bounds__(256) void k_gemm_qkv(const short* __restrict__ A,
                                                  const short* __restrict__ Bt,
                                                  const float* __restrict__ bqp,
                                                  const float* __restrict__ bkp,
                                                  const float* __restrict__ bvp,
                                                  short* __restrict__ qb,
                                                  short* __restrict__ kb,
                                                  short* __restrict__ vt) {
  __shared__ __align__(16) short As[128 * 64];
  __shared__ __align__(16) short Bs[128 * 64];
  const int tid = threadIdx.x;
  const int w = tid >> 6, l = tid & 63;
  const int lg = l >> 4, li = l & 15;
  const int wr = w >> 1, wc = w & 1;
  const int fid = blockIdx.x + 24 * blockIdx.y;
  const int rid = (fid & 7) * 108 + (fid >> 3);
  const int m0 = (rid / 24) * 128, n0 = (rid % 24) * 128;

  f32x4 acc[4][4];
#pragma unroll
  for (int i = 0; i < 4; ++i)
#pragma unroll
    for (int j = 0; j < 4; ++j) acc[i][j] = (f32x4){0.f, 0.f, 0.f, 0.f};

  const int cb = (l & 7) ^ (l >> 3);
  const int rsub = l >> 3;

  for (int kt = 0; kt < 16; ++kt) {
    __syncthreads();
#pragma unroll
    for (int i = 0; i < 4; ++i) {
      int c = w * 4 + i;
      int rr = c * 8 + rsub;
      gload16(A + (size_t)(m0 + rr) * ND + kt * 64 + cb * 8, As + c * 512);
      gload16(Bt + (size_t)(n0 + rr) * ND + kt * 64 + cb * 8, Bs + c * 512);
    }
    __syncthreads();
#pragma unroll
    for (int kk = 0; kk < 2; ++kk) {
      const int blk = (((kk * 4) + lg) ^ (l & 7)) * 8;
      s16x8 af[4], bf[4];
#pragma unroll
      for (int mf = 0; mf < 4; ++mf)
        af[mf] = *(const s16x8*)(As + (wr * 64 + mf * 16 + li) * 64 + blk);
#pragma unroll
      for (int nf = 0; nf < 4; ++nf)
        bf[nf] = *(const s16x8*)(Bs + (wc * 64 + nf * 16 + li) * 64 + blk);
#pragma unroll
      for (int mf = 0; mf < 4; ++mf)
#pragma unroll
        for (int nf = 0; nf < 4; ++nf)
          acc[mf][nf] = mfma16(af[mf], bf[nf], acc[mf][nf]);
    }
  }

#pragma unroll
  for (int mf = 0; mf < 4; ++mf) {
#pragma unroll
    for (int nf = 0; nf < 4; ++nf) {
      const int n = n0 + wc * 64 + nf * 16 + li;
      const int proj = n >> 10, nn = n & 1023;
      const int h = nn >> 6, dd = nn & 63;
      const float bn = (proj == 0 ? bqp : proj == 1 ? bkp : bvp)[nn];
      const int mbase = m0 + wr * 64 + mf * 16 + lg * 4;
      if (proj == 0) {
        // side rows have no Q projection -- guard against OOB
        if (mbase < MMAIN) {
#pragma unroll
          for (int r = 0; r < 4; ++r) {
            int m = mbase + r;
            int b = m >> 11, q = m & 2047;
            qb[((size_t)(b * NH + h) * NQ + q) * DH + dd] =
                (short)f2b((acc[mf][nf][r] + bn) * Q_SCALE);
          }
        }
      } else if (proj == 1) {
#pragma unroll
        for (int r = 0; r < 4; ++r) {
          int m = mbase + r;
          short v = (short)f2b(acc[mf][nf][r] + bn);
          if (m < MMAIN) {
            int b = m >> 11, p = m & 2047;
            kb[((size_t)(b * NH + h) * NL + p) * DH + dd] = v;
          } else {
            int p = NQ + (m - MMAIN);
            kb[((size_t)h * NL + p) * DH + dd] = v;
            kb[((size_t)(NH + h) * NL + p) * DH + dd] = v;
          }
        }
      } else {
        u16x4 vv;
#pragma unroll
        for (int r = 0; r < 4; ++r) vv[r] = f2b(acc[mf][nf][r] + bn);
        if (mbase < MMAIN) {
          int b = mbase >> 11, p = mbase & 2047;
          *(u16x4*)(vt + ((size_t)(b * NH + h) * DH + dd) * NL + p) = vv;
        } else {
          int p = NQ + (mbase - MMAIN);
          *(u16x4*)(vt + ((size_t)h * DH + dd) * NL + p) = vv;
          *(u16x4*)(vt + ((size_t)(NH + h) * DH + dd) * NL + p) = vv;
        }
      }
    }
  }
}

// ---------------- output GEMM: f32 out + bias ----------------
// 128x64 tile, grid (16 n, 32 m) = 512 blocks = 2 blocks/CU. XCD swizzle 512 = 8*64.

__global__ __launch_bounds__(256) void k_gemm_out(const short* __restrict__ A,
                                                  const short* __restrict__ Bt,
                                                  const float* __restrict__ bias,
                                                  float* __restrict__ outp) {
  __shared__ __align__(16) short As[128 * 64];
  __shared__ __align__(16) short Bs[64 * 64];
  const int tid = threadIdx.x;
  const int w = tid >> 6, l = tid & 63;
  const int lg = l >> 4, li = l & 15;
  const int wr = w >> 1, wc = w & 1;
  const int fid = blockIdx.x + 16 * blockIdx.y;
  const int rid = (fid & 7) * 64 + (fid >> 3);
  const int m0 = (rid >> 4) * 128, n0 = (rid & 15) * 64;

  f32x4 acc[4][2];
#pragma unroll
  for (int i = 0; i < 4; ++i)
#pragma unroll
    for (int j = 0; j < 2; ++j) acc[i][j] = (f32x4){0.f, 0.f, 0.f, 0.f};

  const int cb = (l & 7) ^ (l >> 3);
  const int rsub = l >> 3;

  for (int kt = 0; kt < 16; ++kt) {
    __syncthreads();
#pragma unroll
    for (int i = 0; i < 4; ++i) {
      int c = w * 4 + i;
      int rr = c * 8 + rsub;
      gload16(A + (size_t)(m0 + rr) * ND + kt * 64 + cb * 8, As + c * 512);
    }
#pragma unroll
    for (int i = 0; i < 2; ++i) {
      int c = w * 2 + i;
      int rr = c * 8 + rsub;
      gload16(Bt + (size_t)(n0 + rr) * ND + kt * 64 + cb * 8, Bs + c * 512);
    }
    __syncthreads();
#pragma unroll
    for (int kk = 0; kk < 2; ++kk) {
      const int blk = (((kk * 4) + lg) ^ (l & 7)) * 8;
      s16x8 af[4], bf[2];
#pragma unroll
      for (int mf = 0; mf < 4; ++mf)
        af[mf] = *(const s16x8*)(As + (wr * 64 + mf * 16 + li) * 64 + blk);
#pragma unroll
      for (int nf = 0; nf < 2; ++nf)
        bf[nf] = *(const s16x8*)(Bs + (wc * 32 + nf * 16 + li) * 64 + blk);
#pragma unroll
      for (int mf = 0; mf < 4; ++mf)
#pragma unroll
        for (int nf = 0; nf < 2; ++nf)
          acc[mf][nf] = mfma16(af[mf], bf[nf], acc[mf][nf]);
    }
  }

#pragma unroll
  for (int mf = 0; mf < 4; ++mf) {
#pragma unroll
    for (int nf = 0; nf < 2; ++nf) {
      const int n = n0 + wc * 32 + nf * 16 + li;
      const float bn = bias[n];
      const int mbase = m0 + wr * 64 + mf * 16 + lg * 4;
#pragma unroll
      for (int r = 0; r < 4; ++r)
        outp[(size_t)(mbase + r) * ND + n] = acc[mf][nf][r] + bn;
    }
  }
}

// ---------------- flash attention (32x32 MFMA, swapped QK^T, no-max softmax) ----
// grid (bh=32, qt=16), 512 threads = 8 waves = 4 q-subtiles x 2 kv-groups.
// KV tile = 32 rows; LDS 32KB/block -> 2 blocks/CU = 16 waves/CU.
// Sync structure: __syncthreads-per-tile (R12's counted-vmcnt ring raced).

#define PROC_TILE(STV, WSV, PB0, PB1)                                        \
  do {                                                                       \
    unsigned pk_[8];                                                         \
    _Pragma("unroll") for (int r_ = 0; r_ < 16; ++r_) {                      \
      const int c_ = (r_ & 3) + 8 * (r_ >> 2);                               \
      float p_ = exp2r(STV[r_]);                                             \
      p_ = __builtin_bit_cast(float, __builtin_bit_cast(unsigned, p_) &      \
                                         (unsigned)sext_bit(WSV, c_));       \
      lr += p_;                                                              \
      STV[r_] = p_;                                                          \
    }                                                                        \
    _Pragma("unroll") for (int m_ = 0; m_ < 8; ++m_)                         \
        pk_[m_] = cvt_pk_bf16(STV[2 * m_], STV[2 * m_ + 1]);                 \
    plane32_swap(pk_[0], pk_[2]);                                            \
    plane32_swap(pk_[1], pk_[3]);                                            \
    plane32_swap(pk_[4], pk_[6]);                                            \
    plane32_swap(pk_[5], pk_[7]);                                            \
    {                                                                        \
      u32x4 t_ = {pk_[0], pk_[1], pk_[2], pk_[3]};                           \
      PB0 = __builtin_bit_cast(s16x8, t_);                                   \
    }                                                                        \
    {                                                                        \
      u32x4 t_ = {pk_[4], pk_[5], pk_[6], pk_[7]};                           \
      PB1 = __builtin_bit_cast(s16x8, t_);                                   \
    }                                                                        \
  } while (0)

#define ATTN_TILE(CUR, T, DONEXT)                                            \
  do {                                                                       \
    unsigned mw_ = pmrow[(T)];                                               \
    if (DONEXT) {                                                            \
      gload16(kg + (size_t)((T) + 1) * 2048, kl + ((CUR) ^ 1) * 4096);       \
      gload16(vg + ((T) + 1) * 32, vl + ((CUR) ^ 1) * 4096);                 \
    }                                                                        \
    f32x16 st_;                                                              \
    __builtin_amdgcn_s_setprio(1);                                           \
    st_ = mfma32(*(const s16x8*)(ldsg + (CUR) * 4096 + koff[0]), qa[0], ZACC); \
    st_ = mfma32(*(const s16x8*)(ldsg + (CUR) * 4096 + koff[1]), qa[1], st_);  \
    st_ = mfma32(*(const s16x8*)(ldsg + (CUR) * 4096 + koff[2]), qa[2], st_);  \
    st_ = mfma32(*(const s16x8*)(ldsg + (CUR) * 4096 + koff[3]), qa[3], st_);  \
    __builtin_amdgcn_s_setprio(0);                                           \
    unsigned ws_ = mw_ >> (hi * 4);                                          \
    s16x8 pb0_, pb1_;                                                        \
    PROC_TILE(st_, ws_, pb0_, pb1_);                                         \
    __builtin_amdgcn_s_setprio(1);                                           \
    {                                                                        \
      s16x8 v0_ = *(const s16x8*)(ldsg + 8192 + (CUR) * 4096 + voff[0]);     \
      s16x8 v1_ =                                                            \
          *(const s16x8*)(ldsg + 8192 + (CUR) * 4096 + voff[0] + 2048);      \
      ot0 = mfma32(v0_, pb0_, ot0);                                          \
      ot1 = mfma32(v1_, pb0_, ot1);                                          \
    }                                                                        \
    {                                                                        \
      s16x8 v0_ = *(const s16x8*)(ldsg + 8192 + (CUR) * 4096 + voff[1]);     \
      s16x8 v1_ =                                                            \
          *(const s16x8*)(ldsg + 8192 + (CUR) * 4096 + voff[1] + 2048);      \
      ot0 = mfma32(v0_, pb1_, ot0);                                          \
      ot1 = mfma32(v1_, pb1_, ot1);                                          \
    }                                                                        \
    __builtin_amdgcn_s_setprio(0);                                           \
    __syncthreads();                                                         \
  } while (0)

__global__ __launch_bounds__(512, 2) void k_attn2(const short* __restrict__ qbuf,
                                                  const short* __restrict__ kbuf,
                                                  const short* __restrict__ vtbuf,
                                                  const unsigned* __restrict__ pmask,
                                                  short* __restrict__ attbuf) {
  // 32KB: 2 groups x { K[2][32][64] @0, V^T[2][64][32] @8192 }
  __shared__ __align__(16) short lds[16384];
  char* ldsb = (char*)lds;

  const int tid = threadIdx.x;
  const int w = tid >> 6, l = tid & 63;
  const int wg = w & 3, g = w >> 2;  // q-subtile, kv-group
  const int li = l & 31, hi = l >> 5;
  const int bh = blockIdx.x;
  const int b = bh >> 4, h = bh & 15;
  const int qr0 = blockIdx.y * 128 + wg * 32;
  const size_t bhs = (size_t)bh;
  char* ldsg = ldsb + g * 16384;

  // Q fragments (q pre-scaled by log2e/8): lane covers q = qr0+li, d = ks*16+hi*8
  s16x8 qa[4];
  {
    const short* qp = qbuf + (bhs * NQ + qr0 + li) * DH + hi * 8;
#pragma unroll
    for (int ks = 0; ks < 4; ++ks) qa[ks] = *(const s16x8*)(qp + ks * 16);
  }

  // K fragment offsets (rows 128B, XOR(li&7) swizzle): row=li, slice=2ks+hi
  int koff[4];
#pragma unroll
  for (int ks = 0; ks < 4; ++ks)
    koff[ks] = li * 128 + ((((ks << 1) | hi) ^ (li & 7)) << 4);

  // V fragment offsets (rows 64B, XOR((li>>1)&3) swizzle): row=d=li, slice=2ks2+hi
  int voff[2];
#pragma unroll
  for (int ks2 = 0; ks2 < 2; ++ks2)
    voff[ks2] = li * 64 + ((((ks2 << 1) | hi) ^ ((li >> 1) & 3)) << 4);

  // staging (per tile per group: K 4KB + V 4KB; each wave 1KB of each)
  const short* kg = kbuf + (bhs * NL + g * 1280 + wg * 8 + (l >> 3)) * DH +
                    (((l & 7) ^ (l >> 3)) << 3);
  const short* vg = vtbuf + (bhs * DH + wg * 16 + (l >> 2)) * NL + g * 1280 +
                    (((l & 3) ^ ((l >> 3) & 3)) << 3);
  char* kl = ldsg + wg * 1024;
  char* vl = ldsg + 8192 + wg * 1024;

  const unsigned* pmrow = pmask + ((size_t)b * NQ + qr0 + li) * 80 + g * 40;

  const f32x16 ZACC = z16();
  f32x16 ot0 = z16(), ot1 = z16();
  float lr = 0.f;

  // prologue: stage tile 0 into buffer 0
  gload16(kg, kl);
  gload16(vg, vl);
  __syncthreads();

  for (int tt = 0; tt < 20; ++tt) {
    const int t0 = 2 * tt;
    ATTN_TILE(0, t0, 1);
    ATTN_TILE(1, t0 + 1, (t0 + 2 < 40));
  }

  // finish l: this lane held k-rows for its hi half only
  lr += __shfl_xor(lr, 32);

  // ---- combine the two KV groups (exact: no-max partials are additive) ----
  // 2 phases (each phase: 2 waves x 64 lanes x 33 f32 = 16.9KB).
  float* comb = (float*)ldsb;
  const int half = wg >> 1;
  const int slot = ((wg & 1) * 64 + l) * 33;  // stride 33: 2-way alias only
  float lsum = lr;
#pragma unroll
  for (int ph = 0; ph < 2; ++ph) {
    __syncthreads();
    if (g == 1 && half == ph) {
#pragma unroll
      for (int i = 0; i < 16; ++i) comb[slot + i] = ot0[i];
#pragma unroll
      for (int i = 0; i < 16; ++i) comb[slot + 16 + i] = ot1[i];
      comb[slot + 32] = lr;
    }
    __syncthreads();
    if (g == 0 && half == ph) {
#pragma unroll
      for (int i = 0; i < 16; ++i) ot0[i] += comb[slot + i];
#pragma unroll
      for (int i = 0; i < 16; ++i) ot1[i] += comb[slot + 16 + i];
      lsum += comb[slot + 32];
    }
  }
  if (g == 0) {
    const float inv = 1.0f / lsum;
    // epilogue: O^T[d][q] -> attbuf[b,q,h*64+d], d = dt*32 + 8gg + 4hi + r
    short* orow = attbuf + ((size_t)b * NQ + qr0 + li) * ND + h * 64;
#pragma unroll
    for (int gg = 0; gg < 4; ++gg) {
      u16x4 v0, v1;
#pragma unroll
      for (int r = 0; r < 4; ++r) {
        v0[r] = f2b(ot0[gg * 4 + r] * inv);
        v1[r] = f2b(ot1[gg * 4 + r] * inv);
      }
      *(u16x4*)(orow + gg * 8 + hi * 4) = v0;
      *(u16x4*)(orow + 32 + gg * 8 + hi * 4) = v1;
    }
  }
}

// ---------------- host ----------------

extern "C" void kernel_launch(void* const* d_in, const int* in_sizes, int n_in,
                              void* d_out, int out_size, void* d_ws, size_t ws_size,
                              hipStream_t stream) {
  const float* mainp = (const float*)d_in[0];
  const float* sidep = (const float*)d_in[1];
  const int* mask = (const int*)d_in[2];
  const float* Wq = (const float*)d_in[3];
  const float* bq = (const float*)d_in[4];
  const float* Wk = (const float*)d_in[5];
  const float* bk = (const float*)d_in[6];
  const float* Wv = (const float*)d_in[7];
  const float* bv = (const float*)d_in[8];
  const float* Wo = (const float*)d_in[9];
  const float* bo = (const float*)d_in[10];

  char* ws = (char*)d_ws;
  short* xcat   = (short*)(ws + 0);             //  9,437,184 B
  short* Wt     = (short*)(ws + 9437184);       //  8,388,608 B (4x 1024x1024 bf16, n-major)
  short* qbuf   = (short*)(ws + 17825792);      //  8,388,608 B [b,h,q,d]
  short* kbuf   = (short*)(ws + 26214400);      // 10,485,760 B [b,h,pos,d]
  short* vtbuf  = (short*)(ws + 36700160);      // 10,485,760 B [b,h,d,pos]
  short* attbuf = (short*)(ws + 47185920);      //  8,388,608 B [b*q, D]
  unsigned* pmask = (unsigned*)(ws + 55574528); //  1,310,720 B

  k_prep<<<6912, 256, 0, stream>>>(mainp, sidep, mask, Wq, Wk, Wv, Wo,
                                   xcat, Wt, pmask);

  k_gemm_qkv<<<dim3(24, 36), 256, 0, stream>>>(xcat, Wt, bq, bk, bv, qbuf, kbuf, vtbuf);

  k_attn2<<<dim3(32, 16), 512, 0, stream>>>(qbuf, kbuf, vtbuf, pmask, attbuf);

  k_gemm_out<<<dim3(16, 32), 256, 0, stream>>>(attbuf, Wt + 3145728, bo, (float*)d_out);
}